// Round 1
// baseline (367.328 us; speedup 1.0000x reference)
//
#include <hip/hip_runtime.h>
#include <cstdint>

#define B_ 2
#define L_ 2048
#define D_ 1024
#define H_ 16
#define HD_ 64
#define ML_ (B_ * L_)  // 4096 token rows

typedef __bf16 bf16;
typedef __attribute__((ext_vector_type(4))) __bf16 bf16x4;
typedef __attribute__((ext_vector_type(8))) __bf16 bf16x8;
typedef __attribute__((ext_vector_type(4))) float f32x4;

__device__ __forceinline__ f32x4 mfma_16x16x32(bf16x8 a, bf16x8 b, f32x4 c) {
    return __builtin_amdgcn_mfma_f32_16x16x32_bf16(a, b, c, 0, 0, 0);
}

// ---------------- cast x: fp32 -> bf16, 4 elems/thread ----------------
__global__ __launch_bounds__(256) void cast_x_kernel(const float* __restrict__ in,
                                                     bf16* __restrict__ out, int n4) {
    int i = blockIdx.x * blockDim.x + threadIdx.x;
    if (i >= n4) return;
    float4 v = reinterpret_cast<const float4*>(in)[i];
    bf16x4 o;
    o[0] = (bf16)v.x; o[1] = (bf16)v.y; o[2] = (bf16)v.z; o[3] = (bf16)v.w;
    reinterpret_cast<bf16x4*>(out)[i] = o;
}

// ------------- transpose + cast weight: W[k][n] fp32 -> Wt[n][k] bf16 -------------
__global__ __launch_bounds__(1024) void transpose_w_kernel(const float* __restrict__ W,
                                                           bf16* __restrict__ Wt) {
    __shared__ float tile[32][33];
    int n0 = blockIdx.x * 32, k0 = blockIdx.y * 32;
    int tx = threadIdx.x, ty = threadIdx.y;
    tile[ty][tx] = W[(size_t)(k0 + ty) * D_ + n0 + tx];
    __syncthreads();
    Wt[(size_t)(n0 + ty) * D_ + k0 + tx] = (bf16)tile[tx][ty];
}

// ------------- GEMM: C[M,N] = A[M,K] @ Bt[N,K]^T, bf16 in, OutT out -------------
// 64x64 block tile, 4 waves (2x2), each wave 32x32 via 2x2 MFMA 16x16x32 frags.
template <typename OutT>
__global__ __launch_bounds__(256) void gemm_bt_kernel(const bf16* __restrict__ A,
                                                      const bf16* __restrict__ Bt,
                                                      OutT* __restrict__ C,
                                                      int M, int N, int K) {
    __shared__ bf16 As[64][40];  // +8 pad (16B) keeps b128 alignment, breaks bank stride
    __shared__ bf16 Bs[64][40];
    const int nb = N >> 6;
    const int bm = blockIdx.x / nb, bn = blockIdx.x % nb;
    const int m0 = bm << 6, n0 = bn << 6;
    const int t = threadIdx.x;
    const int lane = t & 63;
    const int w = t >> 6;
    const int wm = w >> 1, wn = w & 1;
    const int r = t >> 2, cg = (t & 3) << 3;       // staging: row, k-offset (elems)
    const int fr = lane & 15, fk = (lane >> 4) << 3;  // fragment: row/col, k-offset

    f32x4 acc[2][2] = {};
    for (int k0 = 0; k0 < K; k0 += 32) {
        bf16x8 av = *reinterpret_cast<const bf16x8*>(&A[(size_t)(m0 + r) * K + k0 + cg]);
        bf16x8 bv = *reinterpret_cast<const bf16x8*>(&Bt[(size_t)(n0 + r) * K + k0 + cg]);
        __syncthreads();  // previous iter's fragment reads complete before overwrite
        *reinterpret_cast<bf16x8*>(&As[r][cg]) = av;
        *reinterpret_cast<bf16x8*>(&Bs[r][cg]) = bv;
        __syncthreads();
        bf16x8 af[2], bfr[2];
#pragma unroll
        for (int mt = 0; mt < 2; ++mt)
            af[mt] = *reinterpret_cast<const bf16x8*>(&As[(wm << 5) + (mt << 4) + fr][fk]);
#pragma unroll
        for (int nt = 0; nt < 2; ++nt)
            bfr[nt] = *reinterpret_cast<const bf16x8*>(&Bs[(wn << 5) + (nt << 4) + fr][fk]);
#pragma unroll
        for (int mt = 0; mt < 2; ++mt)
#pragma unroll
            for (int nt = 0; nt < 2; ++nt)
                acc[mt][nt] = mfma_16x16x32(af[mt], bfr[nt], acc[mt][nt]);
    }
    const int col = lane & 15, rq = (lane >> 4) << 2;
#pragma unroll
    for (int mt = 0; mt < 2; ++mt)
#pragma unroll
        for (int nt = 0; nt < 2; ++nt)
#pragma unroll
            for (int reg = 0; reg < 4; ++reg) {
                int rr = m0 + (wm << 5) + (mt << 4) + rq + reg;
                int cc = n0 + (wn << 5) + (nt << 4) + col;
                C[(size_t)rr * N + cc] = (OutT)acc[mt][nt][reg];
            }
}

// ------------- causal flash attention: 1 wave per 16-row Q tile -------------
// Q,K,V,O layout: [B, L, H, HD] == [B, L, D] with head-contiguous 64 elems.
__global__ __launch_bounds__(64) void attn_kernel(const bf16* __restrict__ Q,
                                                  const bf16* __restrict__ Kmat,
                                                  const bf16* __restrict__ V,
                                                  bf16* __restrict__ O) {
    __shared__ bf16 P_lds[16][32];
    const int nqt = L_ / 16;
    const int qt = blockIdx.x % nqt;
    const int h = (blockIdx.x / nqt) % H_;
    const int b = blockIdx.x / (nqt * H_);
    const int lane = threadIdx.x;
    const int lr = lane & 15;
    const int lg = lane >> 4;

    const size_t bb = (size_t)b * L_;
    const int hoff = h * HD_;

    // Q A-fragments: row = lr, k(hd) = lg*8 + i (two K=32 halves of HD=64)
    const bf16* qp = &Q[(bb + qt * 16 + lr) * D_ + hoff + (lg << 3)];
    bf16x8 qf0 = *reinterpret_cast<const bf16x8*>(qp);
    bf16x8 qf1 = *reinterpret_cast<const bf16x8*>(qp + 32);

    f32x4 o[4] = {};
    float mrun[4] = {-1e30f, -1e30f, -1e30f, -1e30f};
    float lsum[4] = {};

    const int rowb = qt * 16 + (lg << 2);
    const int nkb = (qt * 16 + 15) / 32 + 1;  // causal: kv blocks of 32
    for (int kb = 0; kb < nkb; ++kb) {
        const int c0 = kb * 32;
        f32x4 s[2] = {};
#pragma unroll
        for (int sub = 0; sub < 2; ++sub) {
            // K as B^T operand: col = kv position, contiguous hd per lane
            const bf16* kp = &Kmat[(bb + c0 + sub * 16 + lr) * D_ + hoff + (lg << 3)];
            s[sub] = mfma_16x16x32(qf0, *reinterpret_cast<const bf16x8*>(kp), s[sub]);
            s[sub] = mfma_16x16x32(qf1, *reinterpret_cast<const bf16x8*>(kp + 32), s[sub]);
        }
        // online softmax; D layout: col = lr (kv), row = lg*4 + reg (q)
#pragma unroll
        for (int reg = 0; reg < 4; ++reg) {
            const int row = rowb + reg;
            float v0 = (c0 + lr <= row) ? s[0][reg] * 0.125f : -1e30f;
            float v1 = (c0 + 16 + lr <= row) ? s[1][reg] * 0.125f : -1e30f;
            float rm = fmaxf(v0, v1);
            rm = fmaxf(rm, __shfl_xor(rm, 1));
            rm = fmaxf(rm, __shfl_xor(rm, 2));
            rm = fmaxf(rm, __shfl_xor(rm, 4));
            rm = fmaxf(rm, __shfl_xor(rm, 8));
            const float mn = fmaxf(mrun[reg], rm);
            const float p0 = __expf(v0 - mn);
            const float p1 = __expf(v1 - mn);
            float rs = p0 + p1;
            rs += __shfl_xor(rs, 1);
            rs += __shfl_xor(rs, 2);
            rs += __shfl_xor(rs, 4);
            rs += __shfl_xor(rs, 8);
            const float sc = __expf(mrun[reg] - mn);
            lsum[reg] = lsum[reg] * sc + rs;
            mrun[reg] = mn;
#pragma unroll
            for (int nt = 0; nt < 4; ++nt) o[nt][reg] *= sc;
            P_lds[(lg << 2) + reg][lr] = (bf16)p0;
            P_lds[(lg << 2) + reg][16 + lr] = (bf16)p1;
        }
        __syncthreads();
        // P as A operand: row = lr, k(kv) = lg*8 + i
        bf16x8 pa = *reinterpret_cast<const bf16x8*>(&P_lds[lr][lg << 3]);
#pragma unroll
        for (int nt = 0; nt < 4; ++nt) {
            bf16x8 vf;
#pragma unroll
            for (int i = 0; i < 8; ++i)
                vf[i] = V[(bb + c0 + (lg << 3) + i) * D_ + hoff + (nt << 4) + lr];
            o[nt] = mfma_16x16x32(pa, vf, o[nt]);
        }
        __syncthreads();
    }
    float rinv[4];
#pragma unroll
    for (int reg = 0; reg < 4; ++reg) rinv[reg] = 1.0f / lsum[reg];
#pragma unroll
    for (int nt = 0; nt < 4; ++nt)
#pragma unroll
        for (int reg = 0; reg < 4; ++reg) {
            const int row = rowb + reg;
            O[(bb + row) * D_ + hoff + (nt << 4) + lr] = (bf16)(o[nt][reg] * rinv[reg]);
        }
}

extern "C" void kernel_launch(void* const* d_in, const int* in_sizes, int n_in,
                              void* d_out, int out_size, void* d_ws, size_t ws_size,
                              hipStream_t stream) {
    // setup_inputs dict order: x, Wk, Wq, Wv, Wo
    const float* x = (const float*)d_in[0];
    const float* Wk = (const float*)d_in[1];
    const float* Wq = (const float*)d_in[2];
    const float* Wv = (const float*)d_in[3];
    const float* Wo = (const float*)d_in[4];
    float* out = (float*)d_out;

    char* p = (char*)d_ws;
    const size_t xsz = (size_t)ML_ * D_ * sizeof(bf16);  // 8 MB
    const size_t wsz = (size_t)D_ * D_ * sizeof(bf16);   // 2 MB
    bf16* xb = (bf16*)p;  p += xsz;
    bf16* Wqt = (bf16*)p; p += wsz;
    bf16* Wkt = (bf16*)p; p += wsz;
    bf16* Wvt = (bf16*)p; p += wsz;
    bf16* Wot = (bf16*)p; p += wsz;
    bf16* qb = (bf16*)p;  p += xsz;
    bf16* kb = (bf16*)p;  p += xsz;
    bf16* vb = (bf16*)p;  p += xsz;
    bf16* ab = xb;  // x no longer needed after projections; reuse for attn output

    const int n4 = ML_ * D_ / 4;
    cast_x_kernel<<<(n4 + 255) / 256, 256, 0, stream>>>(x, xb, n4);
    dim3 tb(32, 32);
    dim3 tg(D_ / 32, D_ / 32);
    transpose_w_kernel<<<tg, tb, 0, stream>>>(Wq, Wqt);
    transpose_w_kernel<<<tg, tb, 0, stream>>>(Wk, Wkt);
    transpose_w_kernel<<<tg, tb, 0, stream>>>(Wv, Wvt);
    transpose_w_kernel<<<tg, tb, 0, stream>>>(Wo, Wot);

    const int gg = (ML_ / 64) * (D_ / 64);  // 1024 blocks
    gemm_bt_kernel<bf16><<<gg, 256, 0, stream>>>(xb, Wqt, qb, ML_, D_, D_);
    gemm_bt_kernel<bf16><<<gg, 256, 0, stream>>>(xb, Wkt, kb, ML_, D_, D_);
    gemm_bt_kernel<bf16><<<gg, 256, 0, stream>>>(xb, Wvt, vb, ML_, D_, D_);

    attn_kernel<<<B_ * H_ * (L_ / 16), 64, 0, stream>>>(qb, kb, vb, ab);

    gemm_bt_kernel<float><<<gg, 256, 0, stream>>>(ab, Wot, out, ML_, D_, D_);
}

// Round 2
// 297.768 us; speedup vs baseline: 1.2336x; 1.2336x over previous
//
#include <hip/hip_runtime.h>
#include <cstdint>

#define B_ 2
#define L_ 2048
#define D_ 1024
#define H_ 16
#define HD_ 64
#define ML_ (B_ * L_)  // 4096 token rows
#define S_ (3 * D_)    // fused qkv row stride

typedef __bf16 bf16;
typedef __attribute__((ext_vector_type(4))) __bf16 bf16x4;
typedef __attribute__((ext_vector_type(8))) __bf16 bf16x8;
typedef __attribute__((ext_vector_type(4))) float f32x4;

__device__ __forceinline__ f32x4 mfma_16x16x32(bf16x8 a, bf16x8 b, f32x4 c) {
    return __builtin_amdgcn_mfma_f32_16x16x32_bf16(a, b, c, 0, 0, 0);
}

#define GLDS16(g, l)                                                              \
    __builtin_amdgcn_global_load_lds((const __attribute__((address_space(1))) void*)(g), \
                                     (__attribute__((address_space(3))) void*)(l), 16, 0, 0)

// ---------------- cast x: fp32 -> bf16, 4 elems/thread ----------------
__global__ __launch_bounds__(256) void cast_x_kernel(const float* __restrict__ in,
                                                     bf16* __restrict__ out, int n4) {
    int i = blockIdx.x * blockDim.x + threadIdx.x;
    if (i >= n4) return;
    float4 v = reinterpret_cast<const float4*>(in)[i];
    bf16x4 o;
    o[0] = (bf16)v.x; o[1] = (bf16)v.y; o[2] = (bf16)v.z; o[3] = (bf16)v.w;
    reinterpret_cast<bf16x4*>(out)[i] = o;
}

// ------------- transpose + cast weight: W[k][n] fp32 -> Wt[n][k] bf16 -------------
__global__ __launch_bounds__(1024) void transpose_w_kernel(const float* __restrict__ W,
                                                           bf16* __restrict__ Wt) {
    __shared__ float tile[32][33];
    int n0 = blockIdx.x * 32, k0 = blockIdx.y * 32;
    int tx = threadIdx.x, ty = threadIdx.y;
    tile[ty][tx] = W[(size_t)(k0 + ty) * D_ + n0 + tx];
    __syncthreads();
    Wt[(size_t)(n0 + ty) * D_ + k0 + tx] = (bf16)tile[tx][ty];
}

// ------------- GEMM m97-style: C[M,N] = A[M,K] @ Bt[N,K]^T -------------
// 128x128 tile, 4 waves (2x2) each 64x64 (4x4 frags), global_load_lds width=16.
template <typename OutT>
__global__ __launch_bounds__(256) void gemm128_kernel(const bf16* __restrict__ A,
                                                      const bf16* __restrict__ Bt,
                                                      OutT* __restrict__ C,
                                                      int M, int N, int K) {
    __shared__ bf16 As[128][32];  // linear: global_load_lds needs contiguous dest
    __shared__ bf16 Bs[128][32];
    const int nb = N >> 7;
    const int bm = blockIdx.x / nb, bn = blockIdx.x % nb;
    const int m0 = bm << 7, n0 = bn << 7;
    const int t = threadIdx.x;
    const int lane = t & 63;
    const int w = t >> 6;
    const int wm = w >> 1, wn = w & 1;
    const int fr = lane & 15, fk = (lane >> 4) << 3;
    // staging geometry: wave w, call c cover LDS rows w*32+c*16 .. +16;
    // lane l -> row +l/4, col (l%4)*8
    const int srow = (w << 5) + (lane >> 2);
    const int scol = (lane & 3) << 3;

    f32x4 acc[4][4] = {};
    for (int k0 = 0; k0 < K; k0 += 32) {
        const bf16* ga0 = &A[(size_t)(m0 + srow) * K + k0 + scol];
        const bf16* ga1 = &A[(size_t)(m0 + srow + 16) * K + k0 + scol];
        const bf16* gb0 = &Bt[(size_t)(n0 + srow) * K + k0 + scol];
        const bf16* gb1 = &Bt[(size_t)(n0 + srow + 16) * K + k0 + scol];
        __syncthreads();  // prev iter fragment reads done
        GLDS16(ga0, &As[(w << 5)][0]);
        GLDS16(ga1, &As[(w << 5) + 16][0]);
        GLDS16(gb0, &Bs[(w << 5)][0]);
        GLDS16(gb1, &Bs[(w << 5) + 16][0]);
        __syncthreads();  // compiler drains vmcnt before barrier -> tiles ready
        bf16x8 a[4], b[4];
#pragma unroll
        for (int mt = 0; mt < 4; ++mt)
            a[mt] = *reinterpret_cast<const bf16x8*>(&As[(wm << 6) + (mt << 4) + fr][fk]);
#pragma unroll
        for (int nt = 0; nt < 4; ++nt)
            b[nt] = *reinterpret_cast<const bf16x8*>(&Bs[(wn << 6) + (nt << 4) + fr][fk]);
#pragma unroll
        for (int mt = 0; mt < 4; ++mt)
#pragma unroll
            for (int nt = 0; nt < 4; ++nt)
                acc[mt][nt] = mfma_16x16x32(a[mt], b[nt], acc[mt][nt]);
    }
    const int col = lane & 15, rq = (lane >> 4) << 2;
#pragma unroll
    for (int mt = 0; mt < 4; ++mt)
#pragma unroll
        for (int nt = 0; nt < 4; ++nt)
#pragma unroll
            for (int reg = 0; reg < 4; ++reg) {
                int rr = m0 + (wm << 6) + (mt << 4) + rq + reg;
                int cc = n0 + (wn << 6) + (nt << 4) + col;
                C[(size_t)rr * N + cc] = (OutT)acc[mt][nt][reg];
            }
}

// ------------- causal flash attention v2: 4 waves, 64 q-rows/block, KV=64 -------------
// qkv layout: [B*L][3072], Q at col 0, K at 1024, V at 2048; head h at +h*64.
__global__ __launch_bounds__(256) void attn_kernel(const bf16* __restrict__ qkv,
                                                   bf16* __restrict__ O) {
    __shared__ bf16 Ks[64][72];        // [kv][hd]
    __shared__ bf16 Vt[64][72];        // [hd][kv] (transposed)
    __shared__ bf16 P_lds[4][16][72];  // per-wave P tile [qrow][kv]
    const int nqt = L_ / 64;  // 32
    const int qt = blockIdx.x % nqt;
    const int h = (blockIdx.x / nqt) % H_;
    const int b = blockIdx.x / (nqt * H_);
    const int t = threadIdx.x;
    const int lane = t & 63, w = t >> 6;
    const int lr = lane & 15, lg = lane >> 4;
    const size_t bb = (size_t)b * L_;
    const int hoff = h * HD_;
    const int qr0 = qt * 64;

    // staging geometry: thread t covers kv-row r, hd chunks ch*8 and 32+ch*8
    const int r = t >> 2, ch = t & 3;
    const bf16* kbase = &qkv[bb * S_ + D_ + hoff];
    const bf16* vbase = &qkv[bb * S_ + 2 * D_ + hoff];

    // Q fragments (A-operand): row = w*16 + lr, k(hd) = lg*8 + i; two K=32 halves
    const bf16* qp = &qkv[(bb + qr0 + w * 16 + lr) * S_ + hoff + (lg << 3)];
    bf16x8 qf0 = *reinterpret_cast<const bf16x8*>(qp);
    bf16x8 qf1 = *reinterpret_cast<const bf16x8*>(qp + 32);

    f32x4 o[4] = {};
    float mrun[4] = {-1e30f, -1e30f, -1e30f, -1e30f};
    float lsum[4] = {};
    const int qrow = qr0 + w * 16 + (lg << 2);

    const int nkb = qt + 1;
    for (int kb = 0; kb < nkb; ++kb) {
        const int c0 = kb * 64;
        // global -> regs (issued before barrier to hide latency)
        const bf16* kp = kbase + (size_t)(c0 + r) * S_ + ch * 8;
        const bf16* vp = vbase + (size_t)(c0 + r) * S_ + ch * 8;
        bf16x8 k0v = *reinterpret_cast<const bf16x8*>(kp);
        bf16x8 k1v = *reinterpret_cast<const bf16x8*>(kp + 32);
        bf16x8 v0v = *reinterpret_cast<const bf16x8*>(vp);
        bf16x8 v1v = *reinterpret_cast<const bf16x8*>(vp + 32);
        __syncthreads();  // prev iter's Ks/Vt reads complete
        *reinterpret_cast<bf16x8*>(&Ks[r][ch << 3]) = k0v;
        *reinterpret_cast<bf16x8*>(&Ks[r][32 + (ch << 3)]) = k1v;
#pragma unroll
        for (int i = 0; i < 8; ++i) {
            Vt[(ch << 3) + i][r] = v0v[i];
            Vt[32 + (ch << 3) + i][r] = v1v[i];
        }
        __syncthreads();
        // QK^T: s[sub] covers kv cols sub*16..+16
        f32x4 s[4] = {};
#pragma unroll
        for (int sub = 0; sub < 4; ++sub) {
            bf16x8 kf0 = *reinterpret_cast<const bf16x8*>(&Ks[(sub << 4) + lr][lg << 3]);
            bf16x8 kf1 = *reinterpret_cast<const bf16x8*>(&Ks[(sub << 4) + lr][32 + (lg << 3)]);
            s[sub] = mfma_16x16x32(qf0, kf0, s[sub]);
            s[sub] = mfma_16x16x32(qf1, kf1, s[sub]);
        }
        // online softmax: D layout col=lr (kv within sub), row=lg*4+reg (q within 16)
#pragma unroll
        for (int reg = 0; reg < 4; ++reg) {
            const int row = qrow + reg;
            float vv[4];
            float rm = -1e30f;
#pragma unroll
            for (int sub = 0; sub < 4; ++sub) {
                vv[sub] = (c0 + (sub << 4) + lr <= row) ? s[sub][reg] * 0.125f : -1e30f;
                rm = fmaxf(rm, vv[sub]);
            }
            rm = fmaxf(rm, __shfl_xor(rm, 1));
            rm = fmaxf(rm, __shfl_xor(rm, 2));
            rm = fmaxf(rm, __shfl_xor(rm, 4));
            rm = fmaxf(rm, __shfl_xor(rm, 8));
            const float mn = fmaxf(mrun[reg], rm);
            float rs = 0.f;
#pragma unroll
            for (int sub = 0; sub < 4; ++sub) {
                float p = __expf(vv[sub] - mn);
                rs += p;
                P_lds[w][(lg << 2) + reg][(sub << 4) + lr] = (bf16)p;
            }
            rs += __shfl_xor(rs, 1);
            rs += __shfl_xor(rs, 2);
            rs += __shfl_xor(rs, 4);
            rs += __shfl_xor(rs, 8);
            const float sc = __expf(mrun[reg] - mn);
            lsum[reg] = lsum[reg] * sc + rs;
            mrun[reg] = mn;
#pragma unroll
            for (int nt = 0; nt < 4; ++nt) o[nt][reg] *= sc;
        }
        __syncthreads();  // P_lds visible (also orders vs next staging)
        // PV: A = P (row=lr, k=kv), B = V (col=lr within nt, k=kv) via Vt
        bf16x8 pa0 = *reinterpret_cast<const bf16x8*>(&P_lds[w][lr][lg << 3]);
        bf16x8 pa1 = *reinterpret_cast<const bf16x8*>(&P_lds[w][lr][32 + (lg << 3)]);
#pragma unroll
        for (int nt = 0; nt < 4; ++nt) {
            bf16x8 vf0 = *reinterpret_cast<const bf16x8*>(&Vt[(nt << 4) + lr][lg << 3]);
            bf16x8 vf1 = *reinterpret_cast<const bf16x8*>(&Vt[(nt << 4) + lr][32 + (lg << 3)]);
            o[nt] = mfma_16x16x32(pa0, vf0, o[nt]);
            o[nt] = mfma_16x16x32(pa1, vf1, o[nt]);
        }
    }
    float rinv[4];
#pragma unroll
    for (int reg = 0; reg < 4; ++reg) rinv[reg] = 1.0f / lsum[reg];
#pragma unroll
    for (int nt = 0; nt < 4; ++nt)
#pragma unroll
        for (int reg = 0; reg < 4; ++reg)
            O[(bb + qrow + reg) * D_ + hoff + (nt << 4) + lr] = (bf16)(o[nt][reg] * rinv[reg]);
}

extern "C" void kernel_launch(void* const* d_in, const int* in_sizes, int n_in,
                              void* d_out, int out_size, void* d_ws, size_t ws_size,
                              hipStream_t stream) {
    // setup_inputs dict order: x, Wk, Wq, Wv, Wo
    const float* x = (const float*)d_in[0];
    const float* Wk = (const float*)d_in[1];
    const float* Wq = (const float*)d_in[2];
    const float* Wv = (const float*)d_in[3];
    const float* Wo = (const float*)d_in[4];
    float* out = (float*)d_out;

    char* p = (char*)d_ws;
    const size_t xsz = (size_t)ML_ * D_ * sizeof(bf16);   // 8 MB
    const size_t wsz = (size_t)D_ * D_ * sizeof(bf16);    // 2 MB
    bf16* xb = (bf16*)p;   p += xsz;        // x bf16 [4096][1024]
    bf16* Wc = (bf16*)p;   p += 3 * wsz;    // [Wq^T; Wk^T; Wv^T] = [3072][1024]
    bf16* Wot = (bf16*)p;  p += wsz;
    bf16* qkvb = (bf16*)p; p += 3 * xsz;    // [4096][3072]
    bf16* ab = xb;  // attn output reuses x buffer (x dead after qkv GEMM)

    const int n4 = ML_ * D_ / 4;
    cast_x_kernel<<<(n4 + 255) / 256, 256, 0, stream>>>(x, xb, n4);
    dim3 tb(32, 32);
    dim3 tg(D_ / 32, D_ / 32);
    transpose_w_kernel<<<tg, tb, 0, stream>>>(Wq, Wc);
    transpose_w_kernel<<<tg, tb, 0, stream>>>(Wk, Wc + (size_t)D_ * D_);
    transpose_w_kernel<<<tg, tb, 0, stream>>>(Wv, Wc + 2 * (size_t)D_ * D_);
    transpose_w_kernel<<<tg, tb, 0, stream>>>(Wo, Wot);

    // fused QKV projection: [4096][1024] @ [3072][1024]^T -> [4096][3072]
    gemm128_kernel<bf16><<<(ML_ / 128) * (S_ / 128), 256, 0, stream>>>(xb, Wc, qkvb, ML_, S_, D_);

    attn_kernel<<<B_ * H_ * (L_ / 64), 256, 0, stream>>>(qkvb, ab);

    // output projection -> fp32 out
    gemm128_kernel<float><<<(ML_ / 128) * (D_ / 128), 256, 0, stream>>>(ab, Wot, out, ML_, D_, D_);
}